// Round 2
// baseline (8543.462 us; speedup 1.0000x reference)
//
#include <hip/hip_runtime.h>
#include <hip/hip_bf16.h>

typedef __bf16 bf16x8 __attribute__((ext_vector_type(8)));
typedef float f32x4 __attribute__((ext_vector_type(4)));
typedef unsigned short u16;

#define GLD_LDS16(gp, lp) __builtin_amdgcn_global_load_lds( \
    (const __attribute__((address_space(1))) unsigned int*)(gp), \
    (__attribute__((address_space(3))) unsigned int*)(lp), 16, 0, 0)

__device__ __forceinline__ float tanh_fast(float x) {
  float e = __expf(2.0f * x);
  return 1.0f - __fdividef(2.0f, e + 1.0f);
}

__device__ __forceinline__ u16 bf16_rn(float x) {
  union { float f; unsigned u; } v; v.f = x;
  unsigned r = v.u + 0x7fffu + ((v.u >> 16) & 1u);
  return (u16)(r >> 16);
}

// ---------------------------------------------------------------------------
// Fused GEMM: C[M,N] = A[M,K] (bf16 row-major) x Bt[N,K]^T (bf16 row-major)
// 2-phase double-buffered (T3-minimum): prefetch tile t+1 via global_load_lds
// BEFORE computing tile t; the single __syncthreads per K-step supplies the
// vmcnt(0)+barrier. XCD-aware block swizzle (T1): each XCD owns 4 contiguous
// m-rows (all n-tiles) -> per-XCD L2 set = A panels + B <= 4MB.
// MODE 0: out_bf = bf16(tanh(acc + bias + t*wt))
// MODE 1: v = 0.999*y + 0.001*z + h*(acc+bias); out32 = v; out_bf = v
// MODE 2: v = z + h*(acc+bias);                 out32 = v; out_bf = v
// NTL = number of n-tiles (grid.x == 8 * 4 * NTL, M fixed 4096 -> 32 m-tiles)
// ---------------------------------------------------------------------------
template <int BN, int K, int MODE, int NTL>
__global__ __launch_bounds__(256)
void gemm_fused(const u16* __restrict__ A, const u16* __restrict__ Bt,
                const float* __restrict__ bias, const float* __restrict__ wt,
                float tval,
                const float* __restrict__ y_in, const float* __restrict__ z_in,
                float* __restrict__ out32, u16* __restrict__ out_bf, int N) {
  constexpr int BM = 128, BK = 64;
  constexpr int WTN = BN / 2;
  constexpr int FN = WTN / 16;
  constexpr int ACH = BM * BK * 2 / 1024;  // 16 1KB-chunks
  constexpr int BCH = BN * BK * 2 / 1024;  // 16 or 8
  constexpr int NT = K / BK;

  __shared__ u16 As[2][BM * BK];
  __shared__ u16 Bs[2][BN * BK];

  const int tid = threadIdx.x;
  const int wave = tid >> 6;
  const int lane = tid & 63;
  const int wm = wave >> 1, wn = wave & 1;
  const int l15 = lane & 15, kg = lane >> 4;

  // XCD swizzle: HW assigns block i -> XCD i%8. Give each XCD 4 m-rows.
  const int wg = blockIdx.x;
  const int xcd = wg & 7;
  const int j = wg >> 3;
  const int bm0 = (xcd * 4 + j / NTL) * BM;
  const int bn0 = (j % NTL) * BN;

  f32x4 acc[4][FN];
#pragma unroll
  for (int m = 0; m < 4; ++m)
#pragma unroll
    for (int n = 0; n < FN; ++n) acc[m][n] = (f32x4){0.f, 0.f, 0.f, 0.f};

  const int sr = lane >> 3;       // row within 8-row (1KB) chunk
  const int sc = (lane & 7) * 8;  // element offset within row

  const u16* Ag = A + (size_t)bm0 * K;
  const u16* Bg = Bt + (size_t)bn0 * K;

  auto stage = [&](int buf, int kt) {
    const u16* Ak = Ag + kt * BK;
    const u16* Bk = Bg + kt * BK;
#pragma unroll
    for (int i = 0; i < ACH / 4; ++i) {
      const int ch = wave + i * 4;
      GLD_LDS16(Ak + (size_t)(ch * 8 + sr) * K + sc, (char*)As[buf] + ch * 1024);
    }
#pragma unroll
    for (int i = 0; i < BCH / 4; ++i) {
      const int ch = wave + i * 4;
      GLD_LDS16(Bk + (size_t)(ch * 8 + sr) * K + sc, (char*)Bs[buf] + ch * 1024);
    }
  };

  stage(0, 0);
  __syncthreads();  // drain tile 0

  for (int kt = 0; kt < NT; ++kt) {
    const int cur = kt & 1;
    if (kt + 1 < NT) stage(cur ^ 1, kt + 1);  // in flight across compute
#pragma unroll
    for (int ks = 0; ks < 2; ++ks) {
      bf16x8 af[4], bf[FN];
#pragma unroll
      for (int m = 0; m < 4; ++m)
        af[m] = *reinterpret_cast<const bf16x8*>(
            &As[cur][(wm * 64 + m * 16 + l15) * BK + ks * 32 + kg * 8]);
#pragma unroll
      for (int n = 0; n < FN; ++n)
        bf[n] = *reinterpret_cast<const bf16x8*>(
            &Bs[cur][(wn * WTN + n * 16 + l15) * BK + ks * 32 + kg * 8]);
#pragma unroll
      for (int m = 0; m < 4; ++m)
#pragma unroll
        for (int n = 0; n < FN; ++n)
          acc[m][n] =
              __builtin_amdgcn_mfma_f32_16x16x32_bf16(af[m], bf[n], acc[m][n], 0, 0, 0);
    }
    __syncthreads();  // vmcnt(0)+lgkmcnt(0)+barrier: prefetch landed, reads done
  }

  // Epilogue. C/D layout: col = lane&15, row = (lane>>4)*4 + reg.
#pragma unroll
  for (int n = 0; n < FN; ++n) {
    const int col = bn0 + wn * WTN + n * 16 + l15;
    const float bv = bias[col];
    const float wv = (MODE == 0) ? wt[col] : 0.f;
#pragma unroll
    for (int m = 0; m < 4; ++m) {
      const int row0 = bm0 + wm * 64 + m * 16 + kg * 4;
#pragma unroll
      for (int r = 0; r < 4; ++r) {
        const size_t idx = (size_t)(row0 + r) * N + col;
        const float a = acc[m][n][r];
        if (MODE == 0) {
          const float x = a + bv + tval * wv;
          out_bf[idx] = bf16_rn(tanh_fast(x));
        } else if (MODE == 1) {
          const float v = 0.999f * y_in[idx] + 0.001f * z_in[idx] +
                          0.015625f * (a + bv);
          out32[idx] = v;
          out_bf[idx] = bf16_rn(v);
        } else {
          const float v = z_in[idx] + 0.015625f * (a + bv);
          out32[idx] = v;
          out_bf[idx] = bf16_rn(v);
        }
      }
    }
  }
}

// in: [R, C] f32  ->  out: [C, R] bf16
__global__ void transpose_bf16(const float* __restrict__ in, u16* __restrict__ out,
                               int R, int C) {
  __shared__ float tile[32][33];
  const int bx = blockIdx.x * 32;
  const int by = blockIdx.y * 32;
  const int tx = threadIdx.x, ty = threadIdx.y;  // 32 x 8
#pragma unroll
  for (int i = 0; i < 32; i += 8)
    tile[ty + i][tx] = in[(size_t)(by + ty + i) * C + (bx + tx)];
  __syncthreads();
#pragma unroll
  for (int i = 0; i < 32; i += 8)
    out[(size_t)(bx + ty + i) * R + (by + tx)] = bf16_rn(tile[tx][ty + i]);
}

__global__ void init_state(const float* __restrict__ y0, float* __restrict__ y32,
                           float* __restrict__ z32, u16* __restrict__ zbf, int n) {
  const int i = blockIdx.x * blockDim.x + threadIdx.x;
  if (i < n) {
    const float v = y0[i];
    y32[i] = v;
    z32[i] = v;
    zbf[i] = bf16_rn(v);
  }
}

extern "C" void kernel_launch(void* const* d_in, const int* in_sizes, int n_in,
                              void* d_out, int out_size, void* d_ws, size_t ws_size,
                              hipStream_t stream) {
  const float* y0 = (const float*)d_in[0];
  const float* W1 = (const float*)d_in[1];  // [512, 2048]
  const float* b1 = (const float*)d_in[2];  // [2048]
  const float* wt = (const float*)d_in[3];  // [2048]
  const float* W2 = (const float*)d_in[4];  // [2048, 512]
  const float* b2 = (const float*)d_in[5];  // [512]

  constexpr int B = 4096, D = 512, HID = 2048, NSTEP = 64;
  constexpr float Hh = 1.0f / 64.0f;

  char* ws = (char*)d_ws;
  u16* W1t = (u16*)ws; ws += (size_t)HID * D * 2;   // [2048][512] bf16
  u16* W2t = (u16*)ws; ws += (size_t)D * HID * 2;   // [512][2048] bf16
  u16* hid = (u16*)ws; ws += (size_t)B * HID * 2;   // [4096][2048] bf16
  float* z32 = (float*)ws; ws += (size_t)B * D * 4; // [4096][512] f32
  u16* ybf = (u16*)ws; ws += (size_t)B * D * 2;
  u16* zbf = (u16*)ws; ws += (size_t)B * D * 2;
  float* y32 = (float*)d_out;

  transpose_bf16<<<dim3(HID / 32, D / 32), dim3(32, 8), 0, stream>>>(W1, W1t, D, HID);
  transpose_bf16<<<dim3(D / 32, HID / 32), dim3(32, 8), 0, stream>>>(W2, W2t, HID, D);
  init_state<<<(B * D + 255) / 256, 256, 0, stream>>>(y0, y32, z32, zbf, B * D);

  for (int s = 0; s < NSTEP; ++s) {
    const float t0 = (float)s * Hh;
    const float t1 = (float)(s + 1) * Hh;
    // hidden = tanh(z @ W1 + b1 + t0*wt)   grid = 8*4*16 = 512
    gemm_fused<128, 512, 0, 16><<<512, 256, 0, stream>>>(
        zbf, W1t, b1, wt, t0, nullptr, nullptr, nullptr, hid, HID);
    // y = 0.999*y + 0.001*z + h*(hidden @ W2 + b2)   grid = 8*4*8 = 256
    gemm_fused<64, 2048, 1, 8><<<256, 256, 0, stream>>>(
        hid, W2t, b2, nullptr, 0.f, y32, z32, y32, ybf, D);
    // hidden = tanh(y @ W1 + b1 + t1*wt)
    gemm_fused<128, 512, 0, 16><<<512, 256, 0, stream>>>(
        ybf, W1t, b1, wt, t1, nullptr, nullptr, nullptr, hid, HID);
    // z = z + h*(hidden @ W2 + b2)
    gemm_fused<64, 2048, 2, 8><<<256, 256, 0, stream>>>(
        hid, W2t, b2, nullptr, 0.f, nullptr, z32, z32, zbf, D);
  }
}

// Round 3
// 6282.447 us; speedup vs baseline: 1.3599x; 1.3599x over previous
//
#include <hip/hip_runtime.h>
#include <hip/hip_bf16.h>

typedef __bf16 bf16x8 __attribute__((ext_vector_type(8)));
typedef float f32x4 __attribute__((ext_vector_type(4)));
typedef unsigned short u16;

#define GLD_LDS16(gp, lp) __builtin_amdgcn_global_load_lds( \
    (const __attribute__((address_space(1))) unsigned int*)(gp), \
    (__attribute__((address_space(3))) unsigned int*)(lp), 16, 0, 0)

__device__ __forceinline__ float tanh_fast(float x) {
  float e = __expf(2.0f * x);
  return 1.0f - __fdividef(2.0f, e + 1.0f);
}

__device__ __forceinline__ u16 bf16_rn(float x) {
  union { float f; unsigned u; } v; v.f = x;
  unsigned r = v.u + 0x7fffu + ((v.u >> 16) & 1u);
  return (u16)(r >> 16);
}

// ---------------------------------------------------------------------------
// Fused GEMM: C[M,N] = A[M,K] (bf16 row-major) x Bt[N,K]^T (bf16 row-major)
// m97 structure: single-buffered LDS, 2 barriers/K-step, 256 threads (4 waves
// in a 2x2 grid), global_load_lds width-16 staging, 16x16x32 bf16 MFMA.
// Tile BM x BN is a template param:
//   GEMM-A (hidden): 128x128 -> 512 blocks, 2 blocks/CU (m97 regime)
//   GEMM-B (update):  64x64  -> 512 blocks, 2 blocks/CU (was 1 blk/CU, 1 wave/SIMD)
// MODE 0: out_bf = bf16(tanh(acc + bias + t*wt))
// MODE 1: v = 0.999*y + 0.001*z + h*(acc+bias); out32 = v; out_bf = v
// MODE 2: v = z + h*(acc+bias);                 out32 = v; out_bf = v
// ---------------------------------------------------------------------------
template <int BM, int BN, int K, int MODE>
__global__ __launch_bounds__(256)
void gemm_fused(const u16* __restrict__ A, const u16* __restrict__ Bt,
                const float* __restrict__ bias, const float* __restrict__ wt,
                float tval,
                const float* __restrict__ y_in, const float* __restrict__ z_in,
                float* __restrict__ out32, u16* __restrict__ out_bf, int N) {
  constexpr int BK = 64;
  constexpr int WTM = BM / 2, WTN = BN / 2;   // per-wave tile (2x2 wave grid)
  constexpr int FM = WTM / 16, FN = WTN / 16; // fragments per wave
  constexpr int ACH = BM * BK * 2 / 1024;     // 1KB staging chunks
  constexpr int BCH = BN * BK * 2 / 1024;

  __shared__ u16 As[BM * BK];
  __shared__ u16 Bs[BN * BK];

  const int tid = threadIdx.x;
  const int wave = tid >> 6;
  const int lane = tid & 63;
  const int wm = wave >> 1, wn = wave & 1;
  const int l15 = lane & 15, kg = lane >> 4;

  const int bn0 = blockIdx.x * BN;
  const int bm0 = blockIdx.y * BM;

  f32x4 acc[FM][FN];
#pragma unroll
  for (int m = 0; m < FM; ++m)
#pragma unroll
    for (int n = 0; n < FN; ++n) acc[m][n] = (f32x4){0.f, 0.f, 0.f, 0.f};

  const int sr = lane >> 3;       // row within 8-row (1KB) chunk
  const int sc = (lane & 7) * 8;  // element offset within row

  const u16* Ag = A + (size_t)bm0 * K;
  const u16* Bg = Bt + (size_t)bn0 * K;

  for (int kt = 0; kt < K / BK; ++kt) {
    const u16* Ak = Ag + kt * BK;
    const u16* Bk = Bg + kt * BK;
#pragma unroll
    for (int i = 0; i < ACH / 4; ++i) {
      const int ch = wave + i * 4;
      GLD_LDS16(Ak + (size_t)(ch * 8 + sr) * K + sc, (char*)As + ch * 1024);
    }
#pragma unroll
    for (int i = 0; i < BCH / 4; ++i) {
      const int ch = wave + i * 4;
      GLD_LDS16(Bk + (size_t)(ch * 8 + sr) * K + sc, (char*)Bs + ch * 1024);
    }
    __syncthreads();
#pragma unroll
    for (int ks = 0; ks < 2; ++ks) {
      bf16x8 af[FM], bfr[FN];
#pragma unroll
      for (int m = 0; m < FM; ++m)
        af[m] = *reinterpret_cast<const bf16x8*>(
            &As[(wm * WTM + m * 16 + l15) * BK + ks * 32 + kg * 8]);
#pragma unroll
      for (int n = 0; n < FN; ++n)
        bfr[n] = *reinterpret_cast<const bf16x8*>(
            &Bs[(wn * WTN + n * 16 + l15) * BK + ks * 32 + kg * 8]);
#pragma unroll
      for (int m = 0; m < FM; ++m)
#pragma unroll
        for (int n = 0; n < FN; ++n)
          acc[m][n] =
              __builtin_amdgcn_mfma_f32_16x16x32_bf16(af[m], bfr[n], acc[m][n], 0, 0, 0);
    }
    __syncthreads();
  }

  // Epilogue. C/D layout (verified m89/m91): col = lane&15, row = (lane>>4)*4 + reg.
#pragma unroll
  for (int n = 0; n < FN; ++n) {
    const int col = bn0 + wn * WTN + n * 16 + l15;
    const float bv = bias[col];
    const float wv = (MODE == 0) ? wt[col] : 0.f;
#pragma unroll
    for (int m = 0; m < FM; ++m) {
      const int row0 = bm0 + wm * WTM + m * 16 + kg * 4;
#pragma unroll
      for (int r = 0; r < 4; ++r) {
        const size_t idx = (size_t)(row0 + r) * N + col;
        const float a = acc[m][n][r];
        if (MODE == 0) {
          const float x = a + bv + tval * wv;
          out_bf[idx] = bf16_rn(tanh_fast(x));
        } else if (MODE == 1) {
          const float v = 0.999f * y_in[idx] + 0.001f * z_in[idx] +
                          0.015625f * (a + bv);
          out32[idx] = v;
          out_bf[idx] = bf16_rn(v);
        } else {
          const float v = z_in[idx] + 0.015625f * (a + bv);
          out32[idx] = v;
          out_bf[idx] = bf16_rn(v);
        }
      }
    }
  }
}

// in: [R, C] f32  ->  out: [C, R] bf16
__global__ void transpose_bf16(const float* __restrict__ in, u16* __restrict__ out,
                               int R, int C) {
  __shared__ float tile[32][33];
  const int bx = blockIdx.x * 32;
  const int by = blockIdx.y * 32;
  const int tx = threadIdx.x, ty = threadIdx.y;  // 32 x 8
#pragma unroll
  for (int i = 0; i < 32; i += 8)
    tile[ty + i][tx] = in[(size_t)(by + ty + i) * C + (bx + tx)];
  __syncthreads();
#pragma unroll
  for (int i = 0; i < 32; i += 8)
    out[(size_t)(bx + ty + i) * R + (by + tx)] = bf16_rn(tile[tx][ty + i]);
}

__global__ void init_state(const float* __restrict__ y0, float* __restrict__ y32,
                           float* __restrict__ z32, u16* __restrict__ zbf, int n) {
  const int i = blockIdx.x * blockDim.x + threadIdx.x;
  if (i < n) {
    const float v = y0[i];
    y32[i] = v;
    z32[i] = v;
    zbf[i] = bf16_rn(v);
  }
}

extern "C" void kernel_launch(void* const* d_in, const int* in_sizes, int n_in,
                              void* d_out, int out_size, void* d_ws, size_t ws_size,
                              hipStream_t stream) {
  const float* y0 = (const float*)d_in[0];
  const float* W1 = (const float*)d_in[1];  // [512, 2048]
  const float* b1 = (const float*)d_in[2];  // [2048]
  const float* wt = (const float*)d_in[3];  // [2048]
  const float* W2 = (const float*)d_in[4];  // [2048, 512]
  const float* b2 = (const float*)d_in[5];  // [512]

  constexpr int B = 4096, D = 512, HID = 2048, NSTEP = 64;
  constexpr float Hh = 1.0f / 64.0f;

  char* ws = (char*)d_ws;
  u16* W1t = (u16*)ws; ws += (size_t)HID * D * 2;   // [2048][512] bf16
  u16* W2t = (u16*)ws; ws += (size_t)D * HID * 2;   // [512][2048] bf16
  u16* hid = (u16*)ws; ws += (size_t)B * HID * 2;   // [4096][2048] bf16
  float* z32 = (float*)ws; ws += (size_t)B * D * 4; // [4096][512] f32
  u16* ybf = (u16*)ws; ws += (size_t)B * D * 2;
  u16* zbf = (u16*)ws; ws += (size_t)B * D * 2;
  float* y32 = (float*)d_out;

  transpose_bf16<<<dim3(HID / 32, D / 32), dim3(32, 8), 0, stream>>>(W1, W1t, D, HID);
  transpose_bf16<<<dim3(D / 32, HID / 32), dim3(32, 8), 0, stream>>>(W2, W2t, HID, D);
  init_state<<<(B * D + 255) / 256, 256, 0, stream>>>(y0, y32, z32, zbf, B * D);

  for (int s = 0; s < NSTEP; ++s) {
    const float t0 = (float)s * Hh;
    const float t1 = (float)(s + 1) * Hh;
    // hidden = tanh(z @ W1 + b1 + t0*wt)   grid = 16x32 = 512 blocks
    gemm_fused<128, 128, 512, 0><<<dim3(HID / 128, B / 128), 256, 0, stream>>>(
        zbf, W1t, b1, wt, t0, nullptr, nullptr, nullptr, hid, HID);
    // y = 0.999*y + 0.001*z + h*(hidden @ W2 + b2)   grid = 8x64 = 512 blocks
    gemm_fused<64, 64, 2048, 1><<<dim3(D / 64, B / 64), 256, 0, stream>>>(
        hid, W2t, b2, nullptr, 0.f, y32, z32, y32, ybf, D);
    // hidden = tanh(y @ W1 + b1 + t1*wt)
    gemm_fused<128, 128, 512, 0><<<dim3(HID / 128, B / 128), 256, 0, stream>>>(
        ybf, W1t, b1, wt, t1, nullptr, nullptr, nullptr, hid, HID);
    // z = z + h*(hidden @ W2 + b2)
    gemm_fused<64, 64, 2048, 2><<<dim3(D / 64, B / 64), 256, 0, stream>>>(
        hid, W2t, b2, nullptr, 0.f, nullptr, z32, z32, zbf, D);
  }
}

// Round 4
// 5581.763 us; speedup vs baseline: 1.5306x; 1.1255x over previous
//
#include <hip/hip_runtime.h>
#include <hip/hip_bf16.h>

typedef __bf16 bf16x8 __attribute__((ext_vector_type(8)));
typedef float f32x4 __attribute__((ext_vector_type(4)));
typedef unsigned short u16;

#define GLD_LDS16(gp, lp) __builtin_amdgcn_global_load_lds( \
    (const __attribute__((address_space(1))) unsigned int*)(gp), \
    (__attribute__((address_space(3))) unsigned int*)(lp), 16, 0, 0)

__device__ __forceinline__ float tanh_fast(float x) {
  float e = __expf(2.0f * x);
  return 1.0f - __fdividef(2.0f, e + 1.0f);
}

__device__ __forceinline__ u16 bf16_rn(float x) {
  union { float f; unsigned u; } v; v.f = x;
  unsigned r = v.u + 0x7fffu + ((v.u >> 16) & 1u);
  return (u16)(r >> 16);
}

// ---------------------------------------------------------------------------
// Fused GEMM: C[M,N] = A[M,K] (bf16 row-major) x Bt[N,K]^T (bf16 row-major)
// m97 2-barrier structure, BK=128 (half the barrier-drains of BK=64), 256
// threads (4 waves, 2x2), global_load_lds width-16 staging, 16x16x32 MFMA.
// LDS uses [2][rows][64] half-K slabs so the row stride stays 128B (same
// 16-way pattern as the verified BK=64 layout; avoids 32-way at 256B stride).
// XCD swizzle: xcd = wg&7 owns m-tile band [xcd*MPX, (xcd+1)*MPX) x all NTL
// n-tiles -> per-XCD L2 set = A band + full Bt <= 4MB (L2-resident reuse).
// MODE 0: out_bf = bf16(tanh(acc + bias + t*wt))
// MODE 1: v = 0.999*y + 0.001*z + h*(acc+bias); out32 = v; out_bf = v
// MODE 2: v = z + h*(acc+bias);                 out32 = v; out_bf = v
// ---------------------------------------------------------------------------
template <int BM, int BN, int K, int MODE, int NTL>
__global__ __launch_bounds__(256)
void gemm_fused(const u16* __restrict__ A, const u16* __restrict__ Bt,
                const float* __restrict__ bias, const float* __restrict__ wt,
                float tval,
                const float* __restrict__ y_in, const float* __restrict__ z_in,
                float* __restrict__ out32, u16* __restrict__ out_bf, int N) {
  constexpr int BK = 128;
  constexpr int WTM = BM / 2, WTN = BN / 2;   // per-wave tile (2x2 wave grid)
  constexpr int FM = WTM / 16, FN = WTN / 16; // fragments per wave
  constexpr int ACH = BM * BK * 2 / 1024;     // 1KB staging chunks
  constexpr int BCH = BN * BK * 2 / 1024;
  constexpr int CPH_A = BM / 8;               // chunks per half-K slab
  constexpr int CPH_B = BN / 8;
  constexpr int MT = 4096 / BM;               // m-tiles total
  constexpr int MPX = MT / 8;                 // m-tiles per XCD

  __shared__ u16 As[2 * BM * 64];  // [kh][row][64]
  __shared__ u16 Bs[2 * BN * 64];

  const int tid = threadIdx.x;
  const int wave = tid >> 6;
  const int lane = tid & 63;
  const int wm = wave >> 1, wn = wave & 1;
  const int l15 = lane & 15, kg = lane >> 4;

  const int wg = blockIdx.x;
  const int xcd = wg & 7;
  const int j = wg >> 3;
  const int bm0 = (xcd * MPX + j / NTL) * BM;
  const int bn0 = (j % NTL) * BN;

  f32x4 acc[FM][FN];
#pragma unroll
  for (int m = 0; m < FM; ++m)
#pragma unroll
    for (int n = 0; n < FN; ++n) acc[m][n] = (f32x4){0.f, 0.f, 0.f, 0.f};

  const int sr = lane >> 3;       // row within 8-row (1KB) chunk
  const int sc = (lane & 7) * 8;  // element offset within 64-col half-row

  const u16* Ag = A + (size_t)bm0 * K;
  const u16* Bg = Bt + (size_t)bn0 * K;

  for (int kt = 0; kt < K / BK; ++kt) {
    const u16* Ak = Ag + kt * BK;
    const u16* Bk = Bg + kt * BK;
#pragma unroll
    for (int i = 0; i < ACH / 4; ++i) {
      const int ch = wave + i * 4;
      const int kh = ch / CPH_A;   // half-K slab (0/1)
      const int rg = ch % CPH_A;   // 8-row group
      GLD_LDS16(Ak + (size_t)(rg * 8 + sr) * K + kh * 64 + sc,
                (char*)As + ch * 1024);
    }
#pragma unroll
    for (int i = 0; i < BCH / 4; ++i) {
      const int ch = wave + i * 4;
      const int kh = ch / CPH_B;
      const int rg = ch % CPH_B;
      GLD_LDS16(Bk + (size_t)(rg * 8 + sr) * K + kh * 64 + sc,
                (char*)Bs + ch * 1024);
    }
    __syncthreads();
#pragma unroll
    for (int ks = 0; ks < 4; ++ks) {
      const int kh = ks >> 1;
      const int kc = (ks & 1) * 32 + kg * 8;
      bf16x8 af[FM], bfr[FN];
#pragma unroll
      for (int m = 0; m < FM; ++m)
        af[m] = *reinterpret_cast<const bf16x8*>(
            &As[(kh * BM + wm * WTM + m * 16 + l15) * 64 + kc]);
#pragma unroll
      for (int n = 0; n < FN; ++n)
        bfr[n] = *reinterpret_cast<const bf16x8*>(
            &Bs[(kh * BN + wn * WTN + n * 16 + l15) * 64 + kc]);
#pragma unroll
      for (int m = 0; m < FM; ++m)
#pragma unroll
        for (int n = 0; n < FN; ++n)
          acc[m][n] =
              __builtin_amdgcn_mfma_f32_16x16x32_bf16(af[m], bfr[n], acc[m][n], 0, 0, 0);
    }
    __syncthreads();
  }

  // Epilogue. C/D layout (verified m89/m91): col = lane&15, row = (lane>>4)*4 + reg.
#pragma unroll
  for (int n = 0; n < FN; ++n) {
    const int col = bn0 + wn * WTN + n * 16 + l15;
    const float bv = bias[col];
    const float wv = (MODE == 0) ? wt[col] : 0.f;
#pragma unroll
    for (int m = 0; m < FM; ++m) {
      const int row0 = bm0 + wm * WTM + m * 16 + kg * 4;
#pragma unroll
      for (int r = 0; r < 4; ++r) {
        const size_t idx = (size_t)(row0 + r) * N + col;
        const float a = acc[m][n][r];
        if (MODE == 0) {
          const float x = a + bv + tval * wv;
          out_bf[idx] = bf16_rn(tanh_fast(x));
        } else if (MODE == 1) {
          const float v = 0.999f * y_in[idx] + 0.001f * z_in[idx] +
                          0.015625f * (a + bv);
          out32[idx] = v;
          out_bf[idx] = bf16_rn(v);
        } else {
          const float v = z_in[idx] + 0.015625f * (a + bv);
          out32[idx] = v;
          out_bf[idx] = bf16_rn(v);
        }
      }
    }
  }
}

// in: [R, C] f32  ->  out: [C, R] bf16
__global__ void transpose_bf16(const float* __restrict__ in, u16* __restrict__ out,
                               int R, int C) {
  __shared__ float tile[32][33];
  const int bx = blockIdx.x * 32;
  const int by = blockIdx.y * 32;
  const int tx = threadIdx.x, ty = threadIdx.y;  // 32 x 8
#pragma unroll
  for (int i = 0; i < 32; i += 8)
    tile[ty + i][tx] = in[(size_t)(by + ty + i) * C + (bx + tx)];
  __syncthreads();
#pragma unroll
  for (int i = 0; i < 32; i += 8)
    out[(size_t)(bx + ty + i) * R + (by + tx)] = bf16_rn(tile[tx][ty + i]);
}

__global__ void init_state(const float* __restrict__ y0, float* __restrict__ y32,
                           float* __restrict__ z32, u16* __restrict__ zbf, int n) {
  const int i = blockIdx.x * blockDim.x + threadIdx.x;
  if (i < n) {
    const float v = y0[i];
    y32[i] = v;
    z32[i] = v;
    zbf[i] = bf16_rn(v);
  }
}

extern "C" void kernel_launch(void* const* d_in, const int* in_sizes, int n_in,
                              void* d_out, int out_size, void* d_ws, size_t ws_size,
                              hipStream_t stream) {
  const float* y0 = (const float*)d_in[0];
  const float* W1 = (const float*)d_in[1];  // [512, 2048]
  const float* b1 = (const float*)d_in[2];  // [2048]
  const float* wt = (const float*)d_in[3];  // [2048]
  const float* W2 = (const float*)d_in[4];  // [2048, 512]
  const float* b2 = (const float*)d_in[5];  // [512]

  constexpr int B = 4096, D = 512, HID = 2048, NSTEP = 64;
  constexpr float Hh = 1.0f / 64.0f;

  char* ws = (char*)d_ws;
  u16* W1t = (u16*)ws; ws += (size_t)HID * D * 2;   // [2048][512] bf16
  u16* W2t = (u16*)ws; ws += (size_t)D * HID * 2;   // [512][2048] bf16
  u16* hid = (u16*)ws; ws += (size_t)B * HID * 2;   // [4096][2048] bf16
  float* z32 = (float*)ws; ws += (size_t)B * D * 4; // [4096][512] f32
  u16* ybf = (u16*)ws; ws += (size_t)B * D * 2;
  u16* zbf = (u16*)ws; ws += (size_t)B * D * 2;
  float* y32 = (float*)d_out;

  transpose_bf16<<<dim3(HID / 32, D / 32), dim3(32, 8), 0, stream>>>(W1, W1t, D, HID);
  transpose_bf16<<<dim3(D / 32, HID / 32), dim3(32, 8), 0, stream>>>(W2, W2t, HID, D);
  init_state<<<(B * D + 255) / 256, 256, 0, stream>>>(y0, y32, z32, zbf, B * D);

  for (int s = 0; s < NSTEP; ++s) {
    const float t0 = (float)s * Hh;
    const float t1 = (float)(s + 1) * Hh;
    // hidden = tanh(z @ W1 + b1 + t0*wt)   512 blocks (32 m-tiles x 16 n-tiles)
    gemm_fused<128, 128, 512, 0, 16><<<512, 256, 0, stream>>>(
        zbf, W1t, b1, wt, t0, nullptr, nullptr, nullptr, hid, HID);
    // y = 0.999*y + 0.001*z + h*(hidden @ W2 + b2)   512 blocks (64 x 8)
    gemm_fused<64, 64, 2048, 1, 8><<<512, 256, 0, stream>>>(
        hid, W2t, b2, nullptr, 0.f, y32, z32, y32, ybf, D);
    // hidden = tanh(y @ W1 + b1 + t1*wt)
    gemm_fused<128, 128, 512, 0, 16><<<512, 256, 0, stream>>>(
        ybf, W1t, b1, wt, t1, nullptr, nullptr, nullptr, hid, HID);
    // z = z + h*(hidden @ W2 + b2)
    gemm_fused<64, 64, 2048, 2, 8><<<512, 256, 0, stream>>>(
        hid, W2t, b2, nullptr, 0.f, nullptr, z32, z32, zbf, D);
  }
}